// Round 2
// baseline (1041.709 us; speedup 1.0000x reference)
//
#include <hip/hip_runtime.h>

// ---------------------------------------------------------------------------
// TemperSeq2Seq: enc mean-pool -> tanh linear -> 128-step GRU -> 32000-proj
// B=32, S_SRC=256, S_DEC=128, H=256, V=32000
// ---------------------------------------------------------------------------

typedef __attribute__((ext_vector_type(8))) _Float16 f16x8;
typedef __attribute__((ext_vector_type(4))) float f32x4;
typedef unsigned short u16;

#define NBLK_SCAN 16

__device__ __forceinline__ u16 f2h_bits(float v) {
  _Float16 h = (_Float16)v;
  return __builtin_bit_cast(u16, h);
}

// ---------------- device-scope grid barrier (sense-reversing) --------------
__device__ __forceinline__ void gbar(unsigned* bar, unsigned nblk) {
  __syncthreads();
  if (threadIdx.x == 0) {
    __builtin_amdgcn_fence(__ATOMIC_RELEASE, "agent");
    unsigned gen = __hip_atomic_load(&bar[1], __ATOMIC_RELAXED, __HIP_MEMORY_SCOPE_AGENT);
    unsigned arr = __hip_atomic_fetch_add(&bar[0], 1u, __ATOMIC_ACQ_REL, __HIP_MEMORY_SCOPE_AGENT) + 1u;
    if (arr == nblk) {
      __hip_atomic_store(&bar[0], 0u, __ATOMIC_RELAXED, __HIP_MEMORY_SCOPE_AGENT);
      __hip_atomic_store(&bar[1], gen + 1u, __ATOMIC_RELEASE, __HIP_MEMORY_SCOPE_AGENT);
    } else {
      while (__hip_atomic_load(&bar[1], __ATOMIC_RELAXED, __HIP_MEMORY_SCOPE_AGENT) == gen)
        __builtin_amdgcn_s_sleep(1);
    }
    __builtin_amdgcn_fence(__ATOMIC_ACQUIRE, "agent");
  }
  __syncthreads();
}

// ---------------- encoder mean pool: x_rep[b][k] ---------------------------
__global__ void k_enc(const int* __restrict__ x, const float* __restrict__ emb,
                      float* __restrict__ x_rep) {
  int b = blockIdx.x;
  int k = threadIdx.x;
  __shared__ int toks[256];
  toks[threadIdx.x] = x[b * 256 + threadIdx.x];
  __syncthreads();
  float acc = 0.f;
#pragma unroll 8
  for (int s = 0; s < 256; ++s) acc += emb[toks[s] * 256 + k];
  x_rep[b * 256 + k] = acc * (1.f / 256.f);
}

// ---------------- z = tanh(x_rep @ Wt^T + bt) ------------------------------
__global__ void k_z(const float* __restrict__ x_rep, const float* __restrict__ Wt,
                    const float* __restrict__ bt, float* __restrict__ z) {
  __shared__ float xr[256][33];  // [k][b]
  int tid = threadIdx.x;
  for (int i = 0; i < 32; ++i) xr[tid][i] = x_rep[i * 256 + tid];
  __syncthreads();
  int b = tid & 31;
  int j = blockIdx.x * 8 + (tid >> 5);
  float acc = bt[j];
#pragma unroll 4
  for (int k = 0; k < 256; ++k) acc += xr[k][b] * Wt[j * 256 + k];
  z[b * 256 + j] = tanhf(acc);
}

// ---------------- fp32 -> fp16 conversion of W_hh, Wo ----------------------
__global__ void k_prep(const float* __restrict__ whh, const float* __restrict__ wo,
                       u16* __restrict__ whh16, u16* __restrict__ wo16) {
  int idx = blockIdx.x * 256 + threadIdx.x;
  const int total = 768 * 256 + 32000 * 256;  // 8388608
  for (int i = idx; i < total; i += 2048 * 256) {
    if (i < 768 * 256) whh16[i] = f2h_bits(whh[i]);
    else               wo16[i - 768 * 256] = f2h_bits(wo[i - 768 * 256]);
  }
}

// ---------------- gx[j][t*32+b] = W_ih @ (dec_emb[y]+z)^T + b_ih -----------
// fp32 tiled GEMM: M=768(j) x N=4096(t,b), K=256
__global__ __launch_bounds__(256, 2) void k_gx(
    const float* __restrict__ W_ih, const float* __restrict__ b_ih,
    const float* __restrict__ dec_emb, const int* __restrict__ y_in,
    const float* __restrict__ z, float* __restrict__ gx) {
  __shared__ float sA[32][68];  // [k][j]
  __shared__ float sB[32][68];  // [k][n]
  __shared__ int stok[64];
  int tid = threadIdx.x;
  int jt = blockIdx.x % 12, nt = blockIdx.x / 12;
  int j0 = jt * 64, n0 = nt * 64;
  if (tid < 64) {
    int n = n0 + tid;
    stok[tid] = y_in[(n & 31) * 128 + (n >> 5)];
  }
  float acc[4][4] = {};
  int tn = tid & 15, tj = tid >> 4;
  for (int kc = 0; kc < 8; ++kc) {
    int k0 = kc * 32;
    __syncthreads();
#pragma unroll
    for (int qq = 0; qq < 2; ++qq) {
      int q = tid + qq * 256;      // 0..511 float4 slots
      int rr = q >> 3, kq = q & 7; // rr: local row (j or n), kq: float4 within 32k
      float4 va = *(const float4*)&W_ih[(j0 + rr) * 256 + k0 + kq * 4];
      sA[kq * 4 + 0][rr] = va.x; sA[kq * 4 + 1][rr] = va.y;
      sA[kq * 4 + 2][rr] = va.z; sA[kq * 4 + 3][rr] = va.w;
      int b = (n0 + rr) & 31;
      float4 ve = *(const float4*)&dec_emb[stok[rr] * 256 + k0 + kq * 4];
      float4 vz = *(const float4*)&z[b * 256 + k0 + kq * 4];
      sB[kq * 4 + 0][rr] = ve.x + vz.x; sB[kq * 4 + 1][rr] = ve.y + vz.y;
      sB[kq * 4 + 2][rr] = ve.z + vz.z; sB[kq * 4 + 3][rr] = ve.w + vz.w;
    }
    __syncthreads();
#pragma unroll
    for (int k = 0; k < 32; ++k) {
      float4 a4 = *(const float4*)&sA[k][tj * 4];
      float4 b4 = *(const float4*)&sB[k][tn * 4];
      float av[4] = {a4.x, a4.y, a4.z, a4.w};
      float bv[4] = {b4.x, b4.y, b4.z, b4.w};
#pragma unroll
      for (int i = 0; i < 4; ++i)
#pragma unroll
        for (int j2 = 0; j2 < 4; ++j2) acc[i][j2] += av[i] * bv[j2];
    }
  }
#pragma unroll
  for (int i = 0; i < 4; ++i) {
    int j = j0 + tj * 4 + i;
    float bi = b_ih[j];
    float4 o;
    o.x = acc[i][0] + bi; o.y = acc[i][1] + bi;
    o.z = acc[i][2] + bi; o.w = acc[i][3] + bi;
    *(float4*)&gx[j * 4096 + n0 + tn * 4] = o;
  }
}

// ---------------- GRU scan: 128 sequential steps ---------------------------
// 16 blocks x 512 thr. Block g owns hidden units [g*16, g*16+16).
// gh = W_hh_slice(48x256) @ h^T via mfma_f32_16x16x32_f16, W in registers.
__global__ __launch_bounds__(512, 1) void k_scan(
    const u16* __restrict__ whh16, const float* __restrict__ b_hh,
    const float* __restrict__ gx, u16* __restrict__ hbuf,
    u16* __restrict__ Hs, unsigned* __restrict__ bar) {
  int g = blockIdx.x;
  int tid = threadIdx.x;
  int wave = tid >> 6, lane = tid & 63;
  __shared__ float gh_lds[3][16][33];
  __shared__ float h32[16][32];  // [ku][b] fp32 carry

  int m = wave >> 1, nh = wave & 1;  // gate 0..2, batch half 0..1
  f16x8 afrag[8];
  if (wave < 6) {
    int row = m * 256 + g * 16 + (lane & 15);
    int kbase = (lane >> 4) * 8;
#pragma unroll
    for (int s = 0; s < 8; ++s)
      afrag[s] = *(const f16x8*)(whh16 + row * 256 + s * 32 + kbase);
  }
  {  // h = 0 init
    int ku = tid >> 5, b = tid & 31;
    if (tid < 512) {
      h32[ku & 15][b] = 0.f;
    }
    if (tid < 512) {
      hbuf[b * 256 + g * 16 + (ku & 15)] = 0;  // buffer 0, +0.0f in fp16
    }
  }
  gbar(bar, NBLK_SCAN);

  int cur = 0;
  for (int t = 0; t < 128; ++t) {
    if (wave < 6) {
      const u16* hcur = hbuf + cur * 8192;
      int bcol = nh * 16 + (lane & 15);
      int kbase = (lane >> 4) * 8;
      f32x4 acc = {0.f, 0.f, 0.f, 0.f};
#pragma unroll
      for (int s = 0; s < 8; ++s) {
        f16x8 bfrag = *(const f16x8*)(hcur + bcol * 256 + s * 32 + kbase);
        acc = __builtin_amdgcn_mfma_f32_16x16x32_f16(afrag[s], bfrag, acc, 0, 0, 0);
      }
      int kur = (lane >> 4) * 4;
#pragma unroll
      for (int r = 0; r < 4; ++r) gh_lds[m][kur + r][bcol] = acc[r];
    }
    __syncthreads();
    {
      int ku = tid >> 5, b = tid & 31;
      int col = t * 32 + b;
      int row = g * 16 + (ku & 15);
      float gr = gh_lds[0][ku & 15][b] + b_hh[row];
      float gu = gh_lds[1][ku & 15][b] + b_hh[256 + row];
      float gn = gh_lds[2][ku & 15][b] + b_hh[512 + row];
      float xr = gx[row * 4096 + col];
      float xu = gx[(256 + row) * 4096 + col];
      float xn = gx[(512 + row) * 4096 + col];
      float r = 1.f / (1.f + expf(-(xr + gr)));
      float u = 1.f / (1.f + expf(-(xu + gu)));
      float n = tanhf(xn + r * gn);
      float h_new = (1.f - u) * n + u * h32[ku & 15][b];
      h32[ku & 15][b] = h_new;
      u16 hh = f2h_bits(h_new);
      hbuf[(cur ^ 1) * 8192 + b * 256 + row] = hh;
      Hs[(b * 128 + t) * 256 + row] = hh;
    }
    gbar(bar, NBLK_SCAN);
    cur ^= 1;
  }
}

// ---------------- projection: out = Hs @ Wo^T + bo -------------------------
// M=4096, N=32000, K=256, fp16 MFMA, 128x128 tiles, XOR-swizzled LDS
__global__ __launch_bounds__(256, 2) void k_proj(
    const u16* __restrict__ Hs, const u16* __restrict__ wo16,
    const float* __restrict__ bo, float* __restrict__ out) {
  __shared__ u16 sA[8192];  // 128 rows x 64 k (granule-swizzled)
  __shared__ u16 sB[8192];
  int tid = threadIdx.x;
  int wave = tid >> 6, lane = tid & 63;
  int mt = blockIdx.x & 31, nt = blockIdx.x >> 5;
  int m0 = mt << 7, v0 = nt << 7;
  int wm = wave >> 1, wn = wave & 1;

  f32x4 acc[4][4];
#pragma unroll
  for (int i = 0; i < 4; ++i)
#pragma unroll
    for (int j2 = 0; j2 < 4; ++j2) acc[i][j2] = (f32x4){0.f, 0.f, 0.f, 0.f};

  for (int kc = 0; kc < 4; ++kc) {
    int kb = kc << 6;
    __syncthreads();
#pragma unroll
    for (int q = 0; q < 4; ++q) {
      int gr = q * 256 + tid;          // granule 0..1023 (16B each)
      int row = gr >> 3, kg = gr & 7;
      int pg = (gr & ~7) | (kg ^ (row & 7));  // swizzled LDS granule
      f16x8 va = *(const f16x8*)(Hs + (m0 + row) * 256 + kb + kg * 8);
      *(f16x8*)&sA[pg * 8] = va;
      f16x8 vb = *(const f16x8*)(wo16 + (v0 + row) * 256 + kb + kg * 8);
      *(f16x8*)&sB[pg * 8] = vb;
    }
    __syncthreads();
#pragma unroll
    for (int ks = 0; ks < 2; ++ks) {
      f16x8 af[4], bf[4];
      int kg = ks * 4 + (lane >> 4);
#pragma unroll
      for (int i = 0; i < 4; ++i) {
        int row = wm * 64 + i * 16 + (lane & 15);
        af[i] = *(const f16x8*)&sA[(row * 8 + (kg ^ (row & 7))) * 8];
        int vrow = wn * 64 + i * 16 + (lane & 15);
        bf[i] = *(const f16x8*)&sB[(vrow * 8 + (kg ^ (vrow & 7))) * 8];
      }
#pragma unroll
      for (int i = 0; i < 4; ++i)
#pragma unroll
        for (int j2 = 0; j2 < 4; ++j2)
          acc[i][j2] = __builtin_amdgcn_mfma_f32_16x16x32_f16(af[i], bf[j2], acc[i][j2], 0, 0, 0);
    }
  }
  int vcol = v0 + wn * 64 + (lane & 15);
  int rbase = m0 + wm * 64 + (lane >> 4) * 4;
#pragma unroll
  for (int i = 0; i < 4; ++i) {
#pragma unroll
    for (int j2 = 0; j2 < 4; ++j2) {
      int v = vcol + j2 * 16;
      float bias = bo[v];
#pragma unroll
      for (int r = 0; r < 4; ++r) {
        long row = rbase + i * 16 + r;
        out[row * 32000 + v] = acc[i][j2][r] + bias;
      }
    }
  }
}

// ---------------------------------------------------------------------------
extern "C" void kernel_launch(void* const* d_in, const int* in_sizes, int n_in,
                              void* d_out, int out_size, void* d_ws, size_t ws_size,
                              hipStream_t stream) {
  const int*   x       = (const int*)d_in[0];
  const int*   y_in    = (const int*)d_in[1];
  const float* emb     = (const float*)d_in[2];
  const float* dec_emb = (const float*)d_in[3];
  const float* Wt      = (const float*)d_in[4];
  const float* bt      = (const float*)d_in[5];
  const float* W_ih    = (const float*)d_in[6];
  const float* W_hh    = (const float*)d_in[7];
  const float* b_ih    = (const float*)d_in[8];
  const float* b_hh    = (const float*)d_in[9];
  const float* Wo      = (const float*)d_in[10];
  const float* bo      = (const float*)d_in[11];
  float* out = (float*)d_out;
  char* ws = (char*)d_ws;

  unsigned* bar   = (unsigned*)(ws + 0);         // 256 B
  float* x_rep    = (float*)(ws + 256);          // 32*256*4   = 32768
  float* zbuf     = (float*)(ws + 33024);        // 32*256*4   = 32768
  u16*   hbuf     = (u16*)(ws + 65792);          // 2*32*256*2 = 32768
  u16*   Hs       = (u16*)(ws + 98560);          // 4096*256*2 = 2097152
  u16*   whh16    = (u16*)(ws + 2195712);        // 768*256*2  = 393216
  u16*   wo16     = (u16*)(ws + 2588928);        // 32000*256*2= 16384000
  float* gxbuf    = (float*)(ws + 18972928);     // 768*4096*4 = 12582912
  // total: 31555840 bytes

  (void)hipMemsetAsync(bar, 0, 256, stream);
  k_prep<<<2048, 256, 0, stream>>>(W_hh, Wo, whh16, wo16);
  k_enc<<<32, 256, 0, stream>>>(x, emb, x_rep);
  k_z<<<32, 256, 0, stream>>>(x_rep, Wt, bt, zbuf);
  k_gx<<<768, 256, 0, stream>>>(W_ih, b_ih, dec_emb, y_in, zbuf, gxbuf);
  k_scan<<<NBLK_SCAN, 512, 0, stream>>>(whh16, b_hh, gxbuf, hbuf, Hs, bar);
  k_proj<<<8000, 256, 0, stream>>>(Hs, wo16, bo, out);
}

// Round 3
// 810.831 us; speedup vs baseline: 1.2847x; 1.2847x over previous
//
#include <hip/hip_runtime.h>

// ---------------------------------------------------------------------------
// TemperSeq2Seq: enc mean-pool -> tanh linear -> 128-step GRU -> 32000-proj
// B=32, S_SRC=256, S_DEC=128, H=256, V=32000
// ---------------------------------------------------------------------------

typedef __attribute__((ext_vector_type(8))) _Float16 f16x8;
typedef __attribute__((ext_vector_type(4))) float f32x4;
typedef unsigned short u16;

#define NBLK_SCAN 16

__device__ __forceinline__ u16 f2h_bits(float v) {
  _Float16 h = (_Float16)v;
  return __builtin_bit_cast(u16, h);
}

// ---------------- encoder mean pool: x_rep[b][k] ---------------------------
__global__ void k_enc(const int* __restrict__ x, const float* __restrict__ emb,
                      float* __restrict__ x_rep) {
  int b = blockIdx.x;
  int k = threadIdx.x;
  __shared__ int toks[256];
  toks[threadIdx.x] = x[b * 256 + threadIdx.x];
  __syncthreads();
  float acc = 0.f;
#pragma unroll 8
  for (int s = 0; s < 256; ++s) acc += emb[toks[s] * 256 + k];
  x_rep[b * 256 + k] = acc * (1.f / 256.f);
}

// ---------------- z = tanh(x_rep @ Wt^T + bt) ------------------------------
__global__ void k_z(const float* __restrict__ x_rep, const float* __restrict__ Wt,
                    const float* __restrict__ bt, float* __restrict__ z) {
  __shared__ float xr[256][33];  // [k][b]
  int tid = threadIdx.x;
  for (int i = 0; i < 32; ++i) xr[tid][i] = x_rep[i * 256 + tid];
  __syncthreads();
  int b = tid & 31;
  int j = blockIdx.x * 8 + (tid >> 5);
  float acc = bt[j];
#pragma unroll 4
  for (int k = 0; k < 256; ++k) acc += xr[k][b] * Wt[j * 256 + k];
  z[b * 256 + j] = tanhf(acc);
}

// ---------------- fp32 -> fp16 conversion of W_hh, Wo ----------------------
__global__ void k_prep(const float* __restrict__ whh, const float* __restrict__ wo,
                       u16* __restrict__ whh16, u16* __restrict__ wo16) {
  int idx = blockIdx.x * 256 + threadIdx.x;
  const int total = 768 * 256 + 32000 * 256;  // 8388608
  for (int i = idx; i < total; i += 2048 * 256) {
    if (i < 768 * 256) whh16[i] = f2h_bits(whh[i]);
    else               wo16[i - 768 * 256] = f2h_bits(wo[i - 768 * 256]);
  }
}

// ---------------- gx[j][t*32+b] = W_ih @ (dec_emb[y]+z)^T + b_ih -----------
// fp32 tiled GEMM: M=768(j) x N=4096(t,b), K=256
__global__ __launch_bounds__(256, 2) void k_gx(
    const float* __restrict__ W_ih, const float* __restrict__ b_ih,
    const float* __restrict__ dec_emb, const int* __restrict__ y_in,
    const float* __restrict__ z, float* __restrict__ gx) {
  __shared__ float sA[32][68];  // [k][j]
  __shared__ float sB[32][68];  // [k][n]
  __shared__ int stok[64];
  int tid = threadIdx.x;
  int jt = blockIdx.x % 12, nt = blockIdx.x / 12;
  int j0 = jt * 64, n0 = nt * 64;
  if (tid < 64) {
    int n = n0 + tid;
    stok[tid] = y_in[(n & 31) * 128 + (n >> 5)];
  }
  float acc[4][4] = {};
  int tn = tid & 15, tj = tid >> 4;
  for (int kc = 0; kc < 8; ++kc) {
    int k0 = kc * 32;
    __syncthreads();
#pragma unroll
    for (int qq = 0; qq < 2; ++qq) {
      int q = tid + qq * 256;      // 0..511 float4 slots
      int rr = q >> 3, kq = q & 7; // rr: local row (j or n), kq: float4 within 32k
      float4 va = *(const float4*)&W_ih[(j0 + rr) * 256 + k0 + kq * 4];
      sA[kq * 4 + 0][rr] = va.x; sA[kq * 4 + 1][rr] = va.y;
      sA[kq * 4 + 2][rr] = va.z; sA[kq * 4 + 3][rr] = va.w;
      int b = (n0 + rr) & 31;
      float4 ve = *(const float4*)&dec_emb[stok[rr] * 256 + k0 + kq * 4];
      float4 vz = *(const float4*)&z[b * 256 + k0 + kq * 4];
      sB[kq * 4 + 0][rr] = ve.x + vz.x; sB[kq * 4 + 1][rr] = ve.y + vz.y;
      sB[kq * 4 + 2][rr] = ve.z + vz.z; sB[kq * 4 + 3][rr] = ve.w + vz.w;
    }
    __syncthreads();
#pragma unroll
    for (int k = 0; k < 32; ++k) {
      float4 a4 = *(const float4*)&sA[k][tj * 4];
      float4 b4 = *(const float4*)&sB[k][tn * 4];
      float av[4] = {a4.x, a4.y, a4.z, a4.w};
      float bv[4] = {b4.x, b4.y, b4.z, b4.w};
#pragma unroll
      for (int i = 0; i < 4; ++i)
#pragma unroll
        for (int j2 = 0; j2 < 4; ++j2) acc[i][j2] += av[i] * bv[j2];
    }
  }
#pragma unroll
  for (int i = 0; i < 4; ++i) {
    int j = j0 + tj * 4 + i;
    float bi = b_ih[j];
    float4 o;
    o.x = acc[i][0] + bi; o.y = acc[i][1] + bi;
    o.z = acc[i][2] + bi; o.w = acc[i][3] + bi;
    *(float4*)&gx[j * 4096 + n0 + tn * 4] = o;
  }
}

// ---------------- GRU scan: 128 sequential steps ---------------------------
// 16 blocks x 512 thr. Block g owns hidden units [g*16, g*16+16).
// gh = W_hh_slice(48x256) @ h^T via mfma_f32_16x16x32_f16, W in registers.
// ONE flag-array grid barrier per step (store-own-flag + parallel poll);
// double-buffered hbuf makes the second barrier unnecessary.
__global__ __launch_bounds__(512, 1) void k_scan(
    const u16* __restrict__ whh16, const float* __restrict__ b_hh,
    const float* __restrict__ gx, u16* __restrict__ hbuf,
    u16* __restrict__ Hs, unsigned* __restrict__ flags) {
  int g = blockIdx.x;
  int tid = threadIdx.x;
  int wave = tid >> 6, lane = tid & 63;
  __shared__ float gh_lds[3][16][33];
  __shared__ float h32[16][32];  // [ku][b] fp32 carry

  int m = wave >> 1, nh = wave & 1;  // gate 0..2, batch half 0..1
  f16x8 afrag[8];
  if (wave < 6) {
    int row = m * 256 + g * 16 + (lane & 15);
    int kbase = (lane >> 4) * 8;
#pragma unroll
    for (int s = 0; s < 8; ++s)
      afrag[s] = *(const f16x8*)(whh16 + row * 256 + s * 32 + kbase);
  }
  {  // every block zeroes the FULL h buffer 0 (benign same-value race ->
     // no init grid-barrier needed) + fp32 carry
    uint4 zz; zz.x = zz.y = zz.z = zz.w = 0u;
    ((uint4*)hbuf)[tid] = zz;         // bytes [0, 8192)
    ((uint4*)hbuf)[tid + 512] = zz;   // bytes [8192, 16384)
    int ku = tid >> 5, b = tid & 31;
    h32[ku][b] = 0.f;
  }
  __syncthreads();

  int cur = 0;
  int ku = tid >> 5, b = tid & 31;
  int row = g * 16 + ku;
  for (int t = 0; t < 128; ++t) {
    if (wave < 6) {
      const u16* hcur = hbuf + cur * 8192;
      int bcol = nh * 16 + (lane & 15);
      int kbase = (lane >> 4) * 8;
      f32x4 acc = {0.f, 0.f, 0.f, 0.f};
#pragma unroll
      for (int s = 0; s < 8; ++s) {
        f16x8 bfrag = *(const f16x8*)(hcur + bcol * 256 + s * 32 + kbase);
        acc = __builtin_amdgcn_mfma_f32_16x16x32_f16(afrag[s], bfrag, acc, 0, 0, 0);
      }
      int kur = (lane >> 4) * 4;
#pragma unroll
      for (int r = 0; r < 4; ++r) gh_lds[m][kur + r][bcol] = acc[r];
    }
    __syncthreads();
    u16 hh;
    {
      int col = t * 32 + b;
      float gr = gh_lds[0][ku][b] + b_hh[row];
      float gu = gh_lds[1][ku][b] + b_hh[256 + row];
      float gn = gh_lds[2][ku][b] + b_hh[512 + row];
      float xr = gx[row * 4096 + col];
      float xu = gx[(256 + row) * 4096 + col];
      float xn = gx[(512 + row) * 4096 + col];
      float r = 1.f / (1.f + expf(-(xr + gr)));
      float u = 1.f / (1.f + expf(-(xu + gu)));
      float n = tanhf(xn + r * gn);
      float h_new = (1.f - u) * n + u * h32[ku][b];
      h32[ku][b] = h_new;
      hh = f2h_bits(h_new);
      hbuf[(cur ^ 1) * 8192 + b * 256 + row] = hh;
    }
    __syncthreads();  // drains all hbuf stores (vmcnt0 before s_barrier)
    if (tid == 0) {
      __builtin_amdgcn_fence(__ATOMIC_RELEASE, "agent");
      __hip_atomic_store(&flags[g * 4], (unsigned)(t + 1), __ATOMIC_RELAXED,
                         __HIP_MEMORY_SCOPE_AGENT);
    }
    // Hs is only consumed by k_proj after kernel end -> overlap with poll
    Hs[(b * 128 + t) * 256 + row] = hh;
    if (tid < NBLK_SCAN) {
      while (__hip_atomic_load(&flags[tid * 4], __ATOMIC_RELAXED,
                               __HIP_MEMORY_SCOPE_AGENT) < (unsigned)(t + 1)) {
      }
      __builtin_amdgcn_fence(__ATOMIC_ACQUIRE, "agent");
    }
    __syncthreads();
    cur ^= 1;
  }
}

// ---------------- projection: out = Hs @ Wo^T + bo -------------------------
// M=4096, N=32000, K=256, fp16 MFMA, 128x128 tiles, XOR-swizzled LDS
__global__ __launch_bounds__(256, 2) void k_proj(
    const u16* __restrict__ Hs, const u16* __restrict__ wo16,
    const float* __restrict__ bo, float* __restrict__ out) {
  __shared__ u16 sA[8192];  // 128 rows x 64 k (granule-swizzled)
  __shared__ u16 sB[8192];
  int tid = threadIdx.x;
  int wave = tid >> 6, lane = tid & 63;
  int mt = blockIdx.x & 31, nt = blockIdx.x >> 5;
  int m0 = mt << 7, v0 = nt << 7;
  int wm = wave >> 1, wn = wave & 1;

  f32x4 acc[4][4];
#pragma unroll
  for (int i = 0; i < 4; ++i)
#pragma unroll
    for (int j2 = 0; j2 < 4; ++j2) acc[i][j2] = (f32x4){0.f, 0.f, 0.f, 0.f};

  for (int kc = 0; kc < 4; ++kc) {
    int kb = kc << 6;
    __syncthreads();
#pragma unroll
    for (int q = 0; q < 4; ++q) {
      int gr = q * 256 + tid;          // granule 0..1023 (16B each)
      int row = gr >> 3, kg = gr & 7;
      int pg = (gr & ~7) | (kg ^ (row & 7));  // swizzled LDS granule
      f16x8 va = *(const f16x8*)(Hs + (m0 + row) * 256 + kb + kg * 8);
      *(f16x8*)&sA[pg * 8] = va;
      f16x8 vb = *(const f16x8*)(wo16 + (v0 + row) * 256 + kb + kg * 8);
      *(f16x8*)&sB[pg * 8] = vb;
    }
    __syncthreads();
#pragma unroll
    for (int ks = 0; ks < 2; ++ks) {
      f16x8 af[4], bf[4];
      int kg = ks * 4 + (lane >> 4);
#pragma unroll
      for (int i = 0; i < 4; ++i) {
        int row = wm * 64 + i * 16 + (lane & 15);
        af[i] = *(const f16x8*)&sA[(row * 8 + (kg ^ (row & 7))) * 8];
        int vrow = wn * 64 + i * 16 + (lane & 15);
        bf[i] = *(const f16x8*)&sB[(vrow * 8 + (kg ^ (vrow & 7))) * 8];
      }
#pragma unroll
      for (int i = 0; i < 4; ++i)
#pragma unroll
        for (int j2 = 0; j2 < 4; ++j2)
          acc[i][j2] = __builtin_amdgcn_mfma_f32_16x16x32_f16(af[i], bf[j2], acc[i][j2], 0, 0, 0);
    }
  }
  int vcol = v0 + wn * 64 + (lane & 15);
  int rbase = m0 + wm * 64 + (lane >> 4) * 4;
#pragma unroll
  for (int i = 0; i < 4; ++i) {
#pragma unroll
    for (int j2 = 0; j2 < 4; ++j2) {
      int v = vcol + j2 * 16;
      float bias = bo[v];
#pragma unroll
      for (int r = 0; r < 4; ++r) {
        long row = rbase + i * 16 + r;
        out[row * 32000 + v] = acc[i][j2][r] + bias;
      }
    }
  }
}

// ---------------------------------------------------------------------------
extern "C" void kernel_launch(void* const* d_in, const int* in_sizes, int n_in,
                              void* d_out, int out_size, void* d_ws, size_t ws_size,
                              hipStream_t stream) {
  const int*   x       = (const int*)d_in[0];
  const int*   y_in    = (const int*)d_in[1];
  const float* emb     = (const float*)d_in[2];
  const float* dec_emb = (const float*)d_in[3];
  const float* Wt      = (const float*)d_in[4];
  const float* bt      = (const float*)d_in[5];
  const float* W_ih    = (const float*)d_in[6];
  const float* W_hh    = (const float*)d_in[7];
  const float* b_ih    = (const float*)d_in[8];
  const float* b_hh    = (const float*)d_in[9];
  const float* Wo      = (const float*)d_in[10];
  const float* bo      = (const float*)d_in[11];
  float* out = (float*)d_out;
  char* ws = (char*)d_ws;

  unsigned* flags = (unsigned*)(ws + 0);         // 16 slots x 16B = 256 B
  float* x_rep    = (float*)(ws + 256);          // 32*256*4   = 32768
  float* zbuf     = (float*)(ws + 33024);        // 32*256*4   = 32768
  u16*   hbuf     = (u16*)(ws + 65792);          // 2*32*256*2 = 32768
  u16*   Hs       = (u16*)(ws + 98560);          // 4096*256*2 = 2097152
  u16*   whh16    = (u16*)(ws + 2195712);        // 768*256*2  = 393216
  u16*   wo16     = (u16*)(ws + 2588928);        // 32000*256*2= 16384000
  float* gxbuf    = (float*)(ws + 18972928);     // 768*4096*4 = 12582912
  // total: 31555840 bytes

  (void)hipMemsetAsync(flags, 0, 256, stream);
  k_prep<<<2048, 256, 0, stream>>>(W_hh, Wo, whh16, wo16);
  k_enc<<<32, 256, 0, stream>>>(x, emb, x_rep);
  k_z<<<32, 256, 0, stream>>>(x_rep, Wt, bt, zbuf);
  k_gx<<<768, 256, 0, stream>>>(W_ih, b_ih, dec_emb, y_in, zbuf, gxbuf);
  k_scan<<<NBLK_SCAN, 512, 0, stream>>>(whh16, b_hh, gxbuf, hbuf, Hs, flags);
  k_proj<<<8000, 256, 0, stream>>>(Hs, wo16, bo, out);
}

// Round 4
// 450.803 us; speedup vs baseline: 2.3108x; 1.7986x over previous
//
#include <hip/hip_runtime.h>

// ---------------------------------------------------------------------------
// TemperSeq2Seq: enc mean-pool -> tanh linear -> 128-step GRU -> 32000-proj
// B=32, S_SRC=256, S_DEC=128, H=256, V=32000
// GRU scan: batch-split (32 independent recurrences) -> NO grid barrier.
// ---------------------------------------------------------------------------

typedef __attribute__((ext_vector_type(8))) _Float16 f16x8;
typedef __attribute__((ext_vector_type(2))) _Float16 f16x2;
typedef __attribute__((ext_vector_type(4))) float f32x4;
typedef unsigned short u16;

__device__ __forceinline__ u16 f2h_bits(float v) {
  _Float16 h = (_Float16)v;
  return __builtin_bit_cast(u16, h);
}

#if __has_builtin(__builtin_amdgcn_fdot2)
#define FDOT2(a, b, c) __builtin_amdgcn_fdot2((a), (b), (c), false)
#else
#define FDOT2(a, b, c) \
  ((c) + (float)(a)[0] * (float)(b)[0] + (float)(a)[1] * (float)(b)[1])
#endif

// ---------------- encoder mean pool: x_rep[b][k] ---------------------------
__global__ void k_enc(const int* __restrict__ x, const float* __restrict__ emb,
                      float* __restrict__ x_rep) {
  int b = blockIdx.x;
  int k = threadIdx.x;
  __shared__ int toks[256];
  toks[threadIdx.x] = x[b * 256 + threadIdx.x];
  __syncthreads();
  float acc = 0.f;
#pragma unroll 8
  for (int s = 0; s < 256; ++s) acc += emb[toks[s] * 256 + k];
  x_rep[b * 256 + k] = acc * (1.f / 256.f);
}

// ---------------- z = tanh(x_rep @ Wt^T + bt) ------------------------------
__global__ void k_z(const float* __restrict__ x_rep, const float* __restrict__ Wt,
                    const float* __restrict__ bt, float* __restrict__ z) {
  __shared__ float xr[256][33];  // [k][b]
  int tid = threadIdx.x;
  for (int i = 0; i < 32; ++i) xr[tid][i] = x_rep[i * 256 + tid];
  __syncthreads();
  int b = tid & 31;
  int j = blockIdx.x * 8 + (tid >> 5);
  float acc = bt[j];
#pragma unroll 4
  for (int k = 0; k < 256; ++k) acc += xr[k][b] * Wt[j * 256 + k];
  z[b * 256 + j] = tanhf(acc);
}

// ---------------- fp32 -> fp16 conversion of W_hh, Wo ----------------------
__global__ void k_prep(const float* __restrict__ whh, const float* __restrict__ wo,
                       u16* __restrict__ whh16, u16* __restrict__ wo16) {
  int idx = blockIdx.x * 256 + threadIdx.x;
  const int total = 768 * 256 + 32000 * 256;  // 8388608
  for (int i = idx; i < total; i += 2048 * 256) {
    if (i < 768 * 256) whh16[i] = f2h_bits(whh[i]);
    else               wo16[i - 768 * 256] = f2h_bits(wo[i - 768 * 256]);
  }
}

// ---------------- gx2[(t*32+b)*768 + j] = W_ih@(dec_emb[y]+z) + b_ih -------
// fp32 tiled GEMM, output TRANSPOSED for the scan: N=4096 rows x 768 cols
__global__ __launch_bounds__(256, 2) void k_gx(
    const float* __restrict__ W_ih, const float* __restrict__ b_ih,
    const float* __restrict__ dec_emb, const int* __restrict__ y_in,
    const float* __restrict__ z, float* __restrict__ gx2) {
  __shared__ float sA[32][68];  // [k][n]  (dec_emb+z side)
  __shared__ float sB[32][68];  // [k][j]  (W_ih side)
  __shared__ int stok[64];
  int tid = threadIdx.x;
  int jt = blockIdx.x % 12, nt = blockIdx.x / 12;
  int j0 = jt * 64, n0 = nt * 64;
  if (tid < 64) {
    int n = n0 + tid;
    stok[tid] = y_in[(n & 31) * 128 + (n >> 5)];
  }
  float acc[4][4] = {};
  int tn = tid & 15, tj = tid >> 4;  // tj: n-subrow group, tn: j-subcol group
  for (int kc = 0; kc < 8; ++kc) {
    int k0 = kc * 32;
    __syncthreads();
#pragma unroll
    for (int qq = 0; qq < 2; ++qq) {
      int q = tid + qq * 256;      // 0..511 float4 slots
      int rr = q >> 3, kq = q & 7; // rr: local row (n or j), kq: float4 within 32k
      int b = (n0 + rr) & 31;
      float4 ve = *(const float4*)&dec_emb[stok[rr] * 256 + k0 + kq * 4];
      float4 vz = *(const float4*)&z[b * 256 + k0 + kq * 4];
      sA[kq * 4 + 0][rr] = ve.x + vz.x; sA[kq * 4 + 1][rr] = ve.y + vz.y;
      sA[kq * 4 + 2][rr] = ve.z + vz.z; sA[kq * 4 + 3][rr] = ve.w + vz.w;
      float4 vw = *(const float4*)&W_ih[(j0 + rr) * 256 + k0 + kq * 4];
      sB[kq * 4 + 0][rr] = vw.x; sB[kq * 4 + 1][rr] = vw.y;
      sB[kq * 4 + 2][rr] = vw.z; sB[kq * 4 + 3][rr] = vw.w;
    }
    __syncthreads();
#pragma unroll
    for (int k = 0; k < 32; ++k) {
      float4 a4 = *(const float4*)&sA[k][tj * 4];
      float4 b4 = *(const float4*)&sB[k][tn * 4];
      float av[4] = {a4.x, a4.y, a4.z, a4.w};
      float bv[4] = {b4.x, b4.y, b4.z, b4.w};
#pragma unroll
      for (int i = 0; i < 4; ++i)
#pragma unroll
        for (int j2 = 0; j2 < 4; ++j2) acc[i][j2] += av[i] * bv[j2];
    }
  }
  float4 bi = *(const float4*)&b_ih[j0 + tn * 4];
#pragma unroll
  for (int i = 0; i < 4; ++i) {
    int n = n0 + tj * 4 + i;
    float4 o;
    o.x = acc[i][0] + bi.x; o.y = acc[i][1] + bi.y;
    o.z = acc[i][2] + bi.z; o.w = acc[i][3] + bi.w;
    *(float4*)&gx2[n * 768 + j0 + tn * 4] = o;
  }
}

// ---------------- GRU scan: 32 independent blocks (one per batch b) --------
// 512 thr: j = tid&255 (hidden unit), half = tid>>8 (K half).
// W_hh rows {j, 256+j, 512+j} x K-half live in registers (192 VGPR fp16).
// h lives in LDS; per-step GEMV via v_dot2_f32_f16. No global in dep chain.
__global__ __launch_bounds__(512, 2) void k_scan(
    const u16* __restrict__ whh16, const float* __restrict__ b_hh,
    const float* __restrict__ gx2, u16* __restrict__ Hs) {
  int b = blockIdx.x;
  int tid = threadIdx.x;
  int j = tid & 255;
  int half = tid >> 8;

  __shared__ __align__(16) u16 h16[256];
  __shared__ float part[3][256];

  // ---- preload W_hh fragment into registers: w[gate][64] f16x2 ----
  f16x2 w[3][64];
#pragma unroll
  for (int g = 0; g < 3; ++g) {
    const u16* wr = whh16 + (g * 256 + j) * 256 + half * 128;
#pragma unroll
    for (int c = 0; c < 16; ++c) {
      union { f16x8 v8; f16x2 v2[4]; } uu;
      uu.v8 = *(const f16x8*)(wr + c * 8);
      w[g][c * 4 + 0] = uu.v2[0];
      w[g][c * 4 + 1] = uu.v2[1];
      w[g][c * 4 + 2] = uu.v2[2];
      w[g][c * 4 + 3] = uu.v2[3];
    }
  }
  float bh0 = 0.f, bh1 = 0.f, bh2 = 0.f;
  if (half == 0) {
    bh0 = b_hh[j]; bh1 = b_hh[256 + j]; bh2 = b_hh[512 + j];
  }
  if (tid < 256) h16[tid] = 0;  // h = 0
  __syncthreads();

  float h_carry = 0.f;  // fp32 carry of h[j] (half 0 only)
  for (int t = 0; t < 128; ++t) {
    float xr = 0.f, xu = 0.f, xn = 0.f;
    if (half == 0) {  // issue early; consumed after the dot phase
      const float* gp = gx2 + (t * 32 + b) * 768 + j;
      xr = gp[0]; xu = gp[256]; xn = gp[512];
    }
    // ---- 3 dot products over this thread's K half ----
    float a0 = 0.f, a1 = 0.f, a2 = 0.f;
    const f16x8* hv = (const f16x8*)h16;
#pragma unroll
    for (int c = 0; c < 16; ++c) {
      union { f16x8 v8; f16x2 v2[4]; } hu;
      hu.v8 = hv[half * 16 + c];
#pragma unroll
      for (int p = 0; p < 4; ++p) {
        f16x2 hp = hu.v2[p];
        a0 = FDOT2(w[0][c * 4 + p], hp, a0);
        a1 = FDOT2(w[1][c * 4 + p], hp, a1);
        a2 = FDOT2(w[2][c * 4 + p], hp, a2);
      }
    }
    if (half == 1) {
      part[0][j] = a0; part[1][j] = a1; part[2][j] = a2;
    }
    __syncthreads();
    if (half == 0) {
      float gr = a0 + part[0][j] + bh0;
      float gu = a1 + part[1][j] + bh1;
      float gn = a2 + part[2][j] + bh2;
      float r = 1.f / (1.f + expf(-(xr + gr)));
      float u = 1.f / (1.f + expf(-(xu + gu)));
      float n = tanhf(xn + r * gn);
      float h_new = (1.f - u) * n + u * h_carry;
      h_carry = h_new;
      u16 hh = f2h_bits(h_new);
      h16[j] = hh;
      Hs[(b * 128 + t) * 256 + j] = hh;  // fire-and-forget
    }
    __syncthreads();
  }
}

// ---------------- projection: out = Hs @ Wo^T + bo -------------------------
// M=4096, N=32000, K=256, fp16 MFMA, 128x128 tiles, XOR-swizzled LDS
__global__ __launch_bounds__(256, 2) void k_proj(
    const u16* __restrict__ Hs, const u16* __restrict__ wo16,
    const float* __restrict__ bo, float* __restrict__ out) {
  __shared__ u16 sA[8192];  // 128 rows x 64 k (granule-swizzled)
  __shared__ u16 sB[8192];
  int tid = threadIdx.x;
  int wave = tid >> 6, lane = tid & 63;
  int mt = blockIdx.x & 31, nt = blockIdx.x >> 5;
  int m0 = mt << 7, v0 = nt << 7;
  int wm = wave >> 1, wn = wave & 1;

  f32x4 acc[4][4];
#pragma unroll
  for (int i = 0; i < 4; ++i)
#pragma unroll
    for (int j2 = 0; j2 < 4; ++j2) acc[i][j2] = (f32x4){0.f, 0.f, 0.f, 0.f};

  for (int kc = 0; kc < 4; ++kc) {
    int kb = kc << 6;
    __syncthreads();
#pragma unroll
    for (int q = 0; q < 4; ++q) {
      int gr = q * 256 + tid;          // granule 0..1023 (16B each)
      int row = gr >> 3, kg = gr & 7;
      int pg = (gr & ~7) | (kg ^ (row & 7));  // swizzled LDS granule
      f16x8 va = *(const f16x8*)(Hs + (m0 + row) * 256 + kb + kg * 8);
      *(f16x8*)&sA[pg * 8] = va;
      f16x8 vb = *(const f16x8*)(wo16 + (v0 + row) * 256 + kb + kg * 8);
      *(f16x8*)&sB[pg * 8] = vb;
    }
    __syncthreads();
#pragma unroll
    for (int ks = 0; ks < 2; ++ks) {
      f16x8 af[4], bf[4];
      int kg = ks * 4 + (lane >> 4);
#pragma unroll
      for (int i = 0; i < 4; ++i) {
        int row = wm * 64 + i * 16 + (lane & 15);
        af[i] = *(const f16x8*)&sA[(row * 8 + (kg ^ (row & 7))) * 8];
        int vrow = wn * 64 + i * 16 + (lane & 15);
        bf[i] = *(const f16x8*)&sB[(vrow * 8 + (kg ^ (vrow & 7))) * 8];
      }
#pragma unroll
      for (int i = 0; i < 4; ++i)
#pragma unroll
        for (int j2 = 0; j2 < 4; ++j2)
          acc[i][j2] = __builtin_amdgcn_mfma_f32_16x16x32_f16(af[i], bf[j2], acc[i][j2], 0, 0, 0);
    }
  }
  int vcol = v0 + wn * 64 + (lane & 15);
  int rbase = m0 + wm * 64 + (lane >> 4) * 4;
#pragma unroll
  for (int i = 0; i < 4; ++i) {
#pragma unroll
    for (int j2 = 0; j2 < 4; ++j2) {
      int v = vcol + j2 * 16;
      float bias = bo[v];
#pragma unroll
      for (int r = 0; r < 4; ++r) {
        long row = rbase + i * 16 + r;
        out[row * 32000 + v] = acc[i][j2][r] + bias;
      }
    }
  }
}

// ---------------------------------------------------------------------------
extern "C" void kernel_launch(void* const* d_in, const int* in_sizes, int n_in,
                              void* d_out, int out_size, void* d_ws, size_t ws_size,
                              hipStream_t stream) {
  const int*   x       = (const int*)d_in[0];
  const int*   y_in    = (const int*)d_in[1];
  const float* emb     = (const float*)d_in[2];
  const float* dec_emb = (const float*)d_in[3];
  const float* Wt      = (const float*)d_in[4];
  const float* bt      = (const float*)d_in[5];
  const float* W_ih    = (const float*)d_in[6];
  const float* W_hh    = (const float*)d_in[7];
  const float* b_ih    = (const float*)d_in[8];
  const float* b_hh    = (const float*)d_in[9];
  const float* Wo      = (const float*)d_in[10];
  const float* bo      = (const float*)d_in[11];
  float* out = (float*)d_out;
  char* ws = (char*)d_ws;

  float* x_rep    = (float*)(ws + 256);          // 32*256*4   = 32768
  float* zbuf     = (float*)(ws + 33024);        // 32*256*4   = 32768
  u16*   Hs       = (u16*)(ws + 98560);          // 4096*256*2 = 2097152
  u16*   whh16    = (u16*)(ws + 2195712);        // 768*256*2  = 393216
  u16*   wo16     = (u16*)(ws + 2588928);        // 32000*256*2= 16384000
  float* gx2      = (float*)(ws + 18972928);     // 4096*768*4 = 12582912
  // total: 31555840 bytes

  k_prep<<<2048, 256, 0, stream>>>(W_hh, Wo, whh16, wo16);
  k_enc<<<32, 256, 0, stream>>>(x, emb, x_rep);
  k_z<<<32, 256, 0, stream>>>(x_rep, Wt, bt, zbuf);
  k_gx<<<768, 256, 0, stream>>>(W_ih, b_ih, dec_emb, y_in, zbuf, gx2);
  k_scan<<<32, 512, 0, stream>>>(whh16, b_hh, gx2, Hs);
  k_proj<<<8000, 256, 0, stream>>>(Hs, wo16, bo, out);
}

// Round 5
// 361.970 us; speedup vs baseline: 2.8779x; 1.2454x over previous
//
#include <hip/hip_runtime.h>

// ---------------------------------------------------------------------------
// TemperSeq2Seq: enc mean-pool -> tanh linear -> 128-step GRU -> 32000-proj
// B=32, S_SRC=256, S_DEC=128, H=256, V=32000
// GRU scan: batch-split (32 independent recurrences) -> NO grid barrier.
// ---------------------------------------------------------------------------

typedef __attribute__((ext_vector_type(8))) _Float16 f16x8;
typedef __attribute__((ext_vector_type(2))) _Float16 f16x2;
typedef __attribute__((ext_vector_type(4))) float f32x4;
typedef unsigned short u16;

__device__ __forceinline__ u16 f2h_bits(float v) {
  _Float16 h = (_Float16)v;
  return __builtin_bit_cast(u16, h);
}

#if __has_builtin(__builtin_amdgcn_fdot2)
#define FDOT2(a, b, c) __builtin_amdgcn_fdot2((a), (b), (c), false)
#else
#define FDOT2(a, b, c) \
  ((c) + (float)(a)[0] * (float)(b)[0] + (float)(a)[1] * (float)(b)[1])
#endif

// ---------------- fused: {enc mean-pool + z} (blocks 0..31) ----------------
//                  {fp32->fp16 W_hh/Wo convert} (blocks 32..2079)
__global__ __launch_bounds__(256) void k_pe(
    const int* __restrict__ x, const float* __restrict__ emb,
    const float* __restrict__ Wt, const float* __restrict__ bt,
    const float* __restrict__ whh, const float* __restrict__ wo,
    float* __restrict__ z, u16* __restrict__ whh16, u16* __restrict__ wo16) {
  __shared__ int toks[256];
  __shared__ float xrep[256];
  int tid = threadIdx.x;
  if (blockIdx.x < 32) {
    int b = blockIdx.x;
    toks[tid] = x[b * 256 + tid];
    __syncthreads();
    float acc = 0.f;
#pragma unroll 8
    for (int s = 0; s < 256; ++s) acc += emb[toks[s] * 256 + tid];
    xrep[tid] = acc * (1.f / 256.f);
    __syncthreads();
    float zacc = bt[tid];
    const float4* wr = (const float4*)(Wt + tid * 256);
#pragma unroll 8
    for (int c = 0; c < 64; ++c) {
      float4 w4 = wr[c];
      zacc += w4.x * xrep[c * 4 + 0] + w4.y * xrep[c * 4 + 1] +
              w4.z * xrep[c * 4 + 2] + w4.w * xrep[c * 4 + 3];
    }
    z[b * 256 + tid] = tanhf(zacc);
  } else {
    int idx = (blockIdx.x - 32) * 256 + tid;
    const int total = 768 * 256 + 32000 * 256;  // 8388608
    for (int i = idx; i < total; i += 2048 * 256) {
      if (i < 768 * 256) whh16[i] = f2h_bits(whh[i]);
      else               wo16[i - 768 * 256] = f2h_bits(wo[i - 768 * 256]);
    }
  }
}

// ---------------- gx2[(t*32+b)*768 + j] = W_ih@(dec_emb[y]+z) + b_ih -------
// fp32 tiled GEMM, output TRANSPOSED for the scan: N=4096 rows x 768 cols
__global__ __launch_bounds__(256, 2) void k_gx(
    const float* __restrict__ W_ih, const float* __restrict__ b_ih,
    const float* __restrict__ dec_emb, const int* __restrict__ y_in,
    const float* __restrict__ z, float* __restrict__ gx2) {
  __shared__ float sA[32][68];  // [k][n]  (dec_emb+z side)
  __shared__ float sB[32][68];  // [k][j]  (W_ih side)
  __shared__ int stok[64];
  int tid = threadIdx.x;
  int jt = blockIdx.x % 12, nt = blockIdx.x / 12;
  int j0 = jt * 64, n0 = nt * 64;
  if (tid < 64) {
    int n = n0 + tid;
    stok[tid] = y_in[(n & 31) * 128 + (n >> 5)];
  }
  float acc[4][4] = {};
  int tn = tid & 15, tj = tid >> 4;  // tj: n-subrow group, tn: j-subcol group
  for (int kc = 0; kc < 8; ++kc) {
    int k0 = kc * 32;
    __syncthreads();
#pragma unroll
    for (int qq = 0; qq < 2; ++qq) {
      int q = tid + qq * 256;      // 0..511 float4 slots
      int rr = q >> 3, kq = q & 7; // rr: local row (n or j), kq: float4 within 32k
      int b = (n0 + rr) & 31;
      float4 ve = *(const float4*)&dec_emb[stok[rr] * 256 + k0 + kq * 4];
      float4 vz = *(const float4*)&z[b * 256 + k0 + kq * 4];
      sA[kq * 4 + 0][rr] = ve.x + vz.x; sA[kq * 4 + 1][rr] = ve.y + vz.y;
      sA[kq * 4 + 2][rr] = ve.z + vz.z; sA[kq * 4 + 3][rr] = ve.w + vz.w;
      float4 vw = *(const float4*)&W_ih[(j0 + rr) * 256 + k0 + kq * 4];
      sB[kq * 4 + 0][rr] = vw.x; sB[kq * 4 + 1][rr] = vw.y;
      sB[kq * 4 + 2][rr] = vw.z; sB[kq * 4 + 3][rr] = vw.w;
    }
    __syncthreads();
#pragma unroll
    for (int k = 0; k < 32; ++k) {
      float4 a4 = *(const float4*)&sA[k][tj * 4];
      float4 b4 = *(const float4*)&sB[k][tn * 4];
      float av[4] = {a4.x, a4.y, a4.z, a4.w};
      float bv[4] = {b4.x, b4.y, b4.z, b4.w};
#pragma unroll
      for (int i = 0; i < 4; ++i)
#pragma unroll
        for (int j2 = 0; j2 < 4; ++j2) acc[i][j2] += av[i] * bv[j2];
    }
  }
  float4 bi = *(const float4*)&b_ih[j0 + tn * 4];
#pragma unroll
  for (int i = 0; i < 4; ++i) {
    int n = n0 + tj * 4 + i;
    float4 o;
    o.x = acc[i][0] + bi.x; o.y = acc[i][1] + bi.y;
    o.z = acc[i][2] + bi.z; o.w = acc[i][3] + bi.w;
    *(float4*)&gx2[n * 768 + j0 + tn * 4] = o;
  }
}

// ---------------- GRU scan: 32 independent blocks (one per batch b) --------
// 512 thr: j = tid&255 (hidden unit), half = tid>>8 (K half).
// W_hh rows {j, 256+j, 512+j} x K-half live in registers (192 VGPR fp16).
// h lives in LDS; per-step GEMV via v_dot2_f32_f16. No global in dep chain.
__global__ __launch_bounds__(512, 2) void k_scan(
    const u16* __restrict__ whh16, const float* __restrict__ b_hh,
    const float* __restrict__ gx2, u16* __restrict__ Hs) {
  int b = blockIdx.x;
  int tid = threadIdx.x;
  int j = tid & 255;
  int half = tid >> 8;

  __shared__ __align__(16) u16 h16[256];
  __shared__ float part[3][256];

  // ---- preload W_hh fragment into registers: w[gate][64] f16x2 ----
  f16x2 w[3][64];
#pragma unroll
  for (int g = 0; g < 3; ++g) {
    const u16* wr = whh16 + (g * 256 + j) * 256 + half * 128;
#pragma unroll
    for (int c = 0; c < 16; ++c) {
      union { f16x8 v8; f16x2 v2[4]; } uu;
      uu.v8 = *(const f16x8*)(wr + c * 8);
      w[g][c * 4 + 0] = uu.v2[0];
      w[g][c * 4 + 1] = uu.v2[1];
      w[g][c * 4 + 2] = uu.v2[2];
      w[g][c * 4 + 3] = uu.v2[3];
    }
  }
  float bh0 = 0.f, bh1 = 0.f, bh2 = 0.f;
  if (half == 0) {
    bh0 = b_hh[j]; bh1 = b_hh[256 + j]; bh2 = b_hh[512 + j];
  }
  if (tid < 256) h16[tid] = 0;  // h = 0
  __syncthreads();

  float h_carry = 0.f;  // fp32 carry of h[j] (half 0 only)
  for (int t = 0; t < 128; ++t) {
    float xr = 0.f, xu = 0.f, xn = 0.f;
    if (half == 0) {  // issue early; consumed after the dot phase
      const float* gp = gx2 + (t * 32 + b) * 768 + j;
      xr = gp[0]; xu = gp[256]; xn = gp[512];
    }
    // ---- 3 dot products over this thread's K half ----
    float a0 = 0.f, a1 = 0.f, a2 = 0.f;
    const f16x8* hv = (const f16x8*)h16;
#pragma unroll
    for (int c = 0; c < 16; ++c) {
      union { f16x8 v8; f16x2 v2[4]; } hu;
      hu.v8 = hv[half * 16 + c];
#pragma unroll
      for (int p = 0; p < 4; ++p) {
        f16x2 hp = hu.v2[p];
        a0 = FDOT2(w[0][c * 4 + p], hp, a0);
        a1 = FDOT2(w[1][c * 4 + p], hp, a1);
        a2 = FDOT2(w[2][c * 4 + p], hp, a2);
      }
    }
    if (half == 1) {
      part[0][j] = a0; part[1][j] = a1; part[2][j] = a2;
    }
    __syncthreads();
    if (half == 0) {
      float gr = a0 + part[0][j] + bh0;
      float gu = a1 + part[1][j] + bh1;
      float gn = a2 + part[2][j] + bh2;
      float r = 1.f / (1.f + expf(-(xr + gr)));
      float u = 1.f / (1.f + expf(-(xu + gu)));
      float n = tanhf(xn + r * gn);
      float h_new = (1.f - u) * n + u * h_carry;
      h_carry = h_new;
      u16 hh = f2h_bits(h_new);
      h16[j] = hh;
      Hs[(b * 128 + t) * 256 + j] = hh;  // fire-and-forget
    }
    __syncthreads();
  }
}

// ---------------- projection: out = Hs @ Wo^T + bo -------------------------
// M=4096, N=32000, K=256, fp16 MFMA, 128x128 tiles, XOR-swizzled LDS,
// double-buffered + reg-prefetch pipeline, nontemporal output stores.
__global__ __launch_bounds__(256, 2) void k_proj(
    const u16* __restrict__ Hs, const u16* __restrict__ wo16,
    const float* __restrict__ bo, float* __restrict__ out) {
  __shared__ u16 sA[2][8192];  // 128 rows x 64 k (granule-swizzled), x2 buf
  __shared__ u16 sB[2][8192];
  int tid = threadIdx.x;
  int wave = tid >> 6, lane = tid & 63;
  int mt = blockIdx.x & 31, nt = blockIdx.x >> 5;
  int m0 = mt << 7, v0 = nt << 7;
  int wm = wave >> 1, wn = wave & 1;

  f32x4 acc[4][4];
#pragma unroll
  for (int i = 0; i < 4; ++i)
#pragma unroll
    for (int j2 = 0; j2 < 4; ++j2) acc[i][j2] = (f32x4){0.f, 0.f, 0.f, 0.f};

  f16x8 va[4], vb[4];
#define LOADC(kc_)                                                       \
  {                                                                      \
    int kb = (kc_) << 6;                                                 \
    _Pragma("unroll") for (int q = 0; q < 4; ++q) {                      \
      int gr = q * 256 + tid;                                            \
      int row = gr >> 3, kg = gr & 7;                                    \
      va[q] = *(const f16x8*)(Hs + (m0 + row) * 256 + kb + kg * 8);      \
      vb[q] = *(const f16x8*)(wo16 + (v0 + row) * 256 + kb + kg * 8);    \
    }                                                                    \
  }
#define STORELDS(bsel_)                                                  \
  {                                                                      \
    _Pragma("unroll") for (int q = 0; q < 4; ++q) {                      \
      int gr = q * 256 + tid;                                            \
      int row = gr >> 3, kg = gr & 7;                                    \
      int pg = (gr & ~7) | (kg ^ (row & 7));                             \
      *(f16x8*)&sA[bsel_][pg * 8] = va[q];                               \
      *(f16x8*)&sB[bsel_][pg * 8] = vb[q];                               \
    }                                                                    \
  }

  LOADC(0);
  STORELDS(0);
  __syncthreads();

  for (int kc = 0; kc < 4; ++kc) {
    int bsel = kc & 1;
    if (kc < 3) LOADC(kc + 1);  // global loads in flight during MFMA phase
#pragma unroll
    for (int ks = 0; ks < 2; ++ks) {
      f16x8 af[4], bf[4];
      int kg = ks * 4 + (lane >> 4);
#pragma unroll
      for (int i = 0; i < 4; ++i) {
        int row = wm * 64 + i * 16 + (lane & 15);
        af[i] = *(const f16x8*)&sA[bsel][(row * 8 + (kg ^ (row & 7))) * 8];
        int vrow = wn * 64 + i * 16 + (lane & 15);
        bf[i] = *(const f16x8*)&sB[bsel][(vrow * 8 + (kg ^ (vrow & 7))) * 8];
      }
#pragma unroll
      for (int i = 0; i < 4; ++i)
#pragma unroll
        for (int j2 = 0; j2 < 4; ++j2)
          acc[i][j2] = __builtin_amdgcn_mfma_f32_16x16x32_f16(af[i], bf[j2], acc[i][j2], 0, 0, 0);
    }
    if (kc < 3) STORELDS(bsel ^ 1);  // waits vmcnt for va/vb, writes alt buf
    __syncthreads();
  }

  int vcol = v0 + wn * 64 + (lane & 15);
  int rbase = m0 + wm * 64 + (lane >> 4) * 4;
#pragma unroll
  for (int i = 0; i < 4; ++i) {
#pragma unroll
    for (int j2 = 0; j2 < 4; ++j2) {
      int v = vcol + j2 * 16;
      float bias = bo[v];
#pragma unroll
      for (int r = 0; r < 4; ++r) {
        long row = rbase + i * 16 + r;
        __builtin_nontemporal_store(acc[i][j2][r] + bias, &out[row * 32000 + v]);
      }
    }
  }
#undef LOADC
#undef STORELDS
}

// ---------------------------------------------------------------------------
extern "C" void kernel_launch(void* const* d_in, const int* in_sizes, int n_in,
                              void* d_out, int out_size, void* d_ws, size_t ws_size,
                              hipStream_t stream) {
  const int*   x       = (const int*)d_in[0];
  const int*   y_in    = (const int*)d_in[1];
  const float* emb     = (const float*)d_in[2];
  const float* dec_emb = (const float*)d_in[3];
  const float* Wt      = (const float*)d_in[4];
  const float* bt      = (const float*)d_in[5];
  const float* W_ih    = (const float*)d_in[6];
  const float* W_hh    = (const float*)d_in[7];
  const float* b_ih    = (const float*)d_in[8];
  const float* b_hh    = (const float*)d_in[9];
  const float* Wo      = (const float*)d_in[10];
  const float* bo      = (const float*)d_in[11];
  float* out = (float*)d_out;
  char* ws = (char*)d_ws;

  float* zbuf     = (float*)(ws + 33024);        // 32*256*4   = 32768
  u16*   Hs       = (u16*)(ws + 98560);          // 4096*256*2 = 2097152
  u16*   whh16    = (u16*)(ws + 2195712);        // 768*256*2  = 393216
  u16*   wo16     = (u16*)(ws + 2588928);        // 32000*256*2= 16384000
  float* gx2      = (float*)(ws + 18972928);     // 4096*768*4 = 12582912
  // total: 31555840 bytes

  k_pe<<<2080, 256, 0, stream>>>(x, emb, Wt, bt, W_hh, Wo, zbuf, whh16, wo16);
  k_gx<<<768, 256, 0, stream>>>(W_ih, b_ih, dec_emb, y_in, zbuf, gx2);
  k_scan<<<32, 512, 0, stream>>>(whh16, b_hh, gx2, Hs);
  k_proj<<<8000, 256, 0, stream>>>(Hs, wo16, bo, out);
}

// Round 6
// 338.547 us; speedup vs baseline: 3.0770x; 1.0692x over previous
//
#include <hip/hip_runtime.h>

// ---------------------------------------------------------------------------
// TemperSeq2Seq: enc mean-pool -> tanh linear -> 128-step GRU -> 32000-proj
// B=32, S_SRC=256, S_DEC=128, H=256, V=32000
// Megakernel: GRU scan (blocks 0..31) OVERLAPPED with projection (blocks
// 32..8031) via per-batch progress flags. Hs stored t-major (row = t*32+b).
// ---------------------------------------------------------------------------

typedef __attribute__((ext_vector_type(8))) _Float16 f16x8;
typedef __attribute__((ext_vector_type(2))) _Float16 f16x2;
typedef __attribute__((ext_vector_type(4))) float f32x4;
typedef unsigned short u16;

__device__ __forceinline__ u16 f2h_bits(float v) {
  _Float16 h = (_Float16)v;
  return __builtin_bit_cast(u16, h);
}

#if __has_builtin(__builtin_amdgcn_fdot2)
#define FDOT2(a, b, c) __builtin_amdgcn_fdot2((a), (b), (c), false)
#else
#define FDOT2(a, b, c) \
  ((c) + (float)(a)[0] * (float)(b)[0] + (float)(a)[1] * (float)(b)[1])
#endif

// ---------------- fused: {enc mean-pool + z} (blocks 0..31) ----------------
//                  {fp32->fp16 W_hh/Wo convert} (blocks 32..2079)
__global__ __launch_bounds__(256) void k_pe(
    const int* __restrict__ x, const float* __restrict__ emb,
    const float* __restrict__ Wt, const float* __restrict__ bt,
    const float* __restrict__ whh, const float* __restrict__ wo,
    float* __restrict__ z, u16* __restrict__ whh16, u16* __restrict__ wo16) {
  __shared__ int toks[256];
  __shared__ float xrep[256];
  int tid = threadIdx.x;
  if (blockIdx.x < 32) {
    int b = blockIdx.x;
    toks[tid] = x[b * 256 + tid];
    __syncthreads();
    float acc = 0.f;
#pragma unroll 8
    for (int s = 0; s < 256; ++s) acc += emb[toks[s] * 256 + tid];
    xrep[tid] = acc * (1.f / 256.f);
    __syncthreads();
    float zacc = bt[tid];
    const float4* wr = (const float4*)(Wt + tid * 256);
#pragma unroll 8
    for (int c = 0; c < 64; ++c) {
      float4 w4 = wr[c];
      zacc += w4.x * xrep[c * 4 + 0] + w4.y * xrep[c * 4 + 1] +
              w4.z * xrep[c * 4 + 2] + w4.w * xrep[c * 4 + 3];
    }
    z[b * 256 + tid] = tanhf(zacc);
  } else {
    int idx = (blockIdx.x - 32) * 256 + tid;
    const int total = 768 * 256 + 32000 * 256;  // 8388608
    for (int i = idx; i < total; i += 2048 * 256) {
      if (i < 768 * 256) whh16[i] = f2h_bits(whh[i]);
      else               wo16[i - 768 * 256] = f2h_bits(wo[i - 768 * 256]);
    }
  }
}

// ---------------- gx2[(t*32+b)*768 + j] = W_ih@(dec_emb[y]+z) + b_ih -------
// fp32 tiled GEMM, output TRANSPOSED for the scan: N=4096 rows x 768 cols
__global__ __launch_bounds__(256, 2) void k_gx(
    const float* __restrict__ W_ih, const float* __restrict__ b_ih,
    const float* __restrict__ dec_emb, const int* __restrict__ y_in,
    const float* __restrict__ z, float* __restrict__ gx2) {
  __shared__ float sA[32][68];  // [k][n]  (dec_emb+z side)
  __shared__ float sB[32][68];  // [k][j]  (W_ih side)
  __shared__ int stok[64];
  int tid = threadIdx.x;
  int jt = blockIdx.x % 12, nt = blockIdx.x / 12;
  int j0 = jt * 64, n0 = nt * 64;
  if (tid < 64) {
    int n = n0 + tid;
    stok[tid] = y_in[(n & 31) * 128 + (n >> 5)];
  }
  float acc[4][4] = {};
  int tn = tid & 15, tj = tid >> 4;  // tj: n-subrow group, tn: j-subcol group
  for (int kc = 0; kc < 8; ++kc) {
    int k0 = kc * 32;
    __syncthreads();
#pragma unroll
    for (int qq = 0; qq < 2; ++qq) {
      int q = tid + qq * 256;      // 0..511 float4 slots
      int rr = q >> 3, kq = q & 7; // rr: local row (n or j), kq: float4 within 32k
      int b = (n0 + rr) & 31;
      float4 ve = *(const float4*)&dec_emb[stok[rr] * 256 + k0 + kq * 4];
      float4 vz = *(const float4*)&z[b * 256 + k0 + kq * 4];
      sA[kq * 4 + 0][rr] = ve.x + vz.x; sA[kq * 4 + 1][rr] = ve.y + vz.y;
      sA[kq * 4 + 2][rr] = ve.z + vz.z; sA[kq * 4 + 3][rr] = ve.w + vz.w;
      float4 vw = *(const float4*)&W_ih[(j0 + rr) * 256 + k0 + kq * 4];
      sB[kq * 4 + 0][rr] = vw.x; sB[kq * 4 + 1][rr] = vw.y;
      sB[kq * 4 + 2][rr] = vw.z; sB[kq * 4 + 3][rr] = vw.w;
    }
    __syncthreads();
#pragma unroll
    for (int k = 0; k < 32; ++k) {
      float4 a4 = *(const float4*)&sA[k][tj * 4];
      float4 b4 = *(const float4*)&sB[k][tn * 4];
      float av[4] = {a4.x, a4.y, a4.z, a4.w};
      float bv[4] = {b4.x, b4.y, b4.z, b4.w};
#pragma unroll
      for (int i = 0; i < 4; ++i)
#pragma unroll
        for (int j2 = 0; j2 < 4; ++j2) acc[i][j2] += av[i] * bv[j2];
    }
  }
  float4 bi = *(const float4*)&b_ih[j0 + tn * 4];
#pragma unroll
  for (int i = 0; i < 4; ++i) {
    int n = n0 + tj * 4 + i;
    float4 o;
    o.x = acc[i][0] + bi.x; o.y = acc[i][1] + bi.y;
    o.z = acc[i][2] + bi.z; o.w = acc[i][3] + bi.w;
    *(float4*)&gx2[n * 768 + j0 + tn * 4] = o;
  }
}

// ---------------- MEGAKERNEL: scan (blocks 0..31) + proj (blocks 32..8031) -
// scan: 512 thr, batch b = blockIdx. j = tid&255, half = tid>>8.
//   W_hh rows {j,256+j,512+j} x K-half in regs; h in LDS; dot2 GEMV.
//   Hs row = t*32+b; flag[b] = t+1 released every 4 steps.
// proj: tile (mt,nt) of out = Hs @ Wo^T + bo. M=4096(t,b) x N=32000, K=256.
//   Polls flags until all batches passed step 4*mt+4. 8 waves x (32x64).
//   Double-buffered swizzled LDS + reg prefetch, NT stores.
__global__ __launch_bounds__(512, 2) void k_mega(
    const u16* __restrict__ whh16, const float* __restrict__ b_hh,
    const float* __restrict__ gx2, u16* __restrict__ Hs,
    const u16* __restrict__ wo16, const float* __restrict__ bo,
    float* __restrict__ out, unsigned* __restrict__ flags) {
  __shared__ __align__(16) u16 sA[2][8192];   // proj: 128 rows x 64 k, x2
  __shared__ __align__(16) u16 sB[2][8192];
  int tid = threadIdx.x;

  if (blockIdx.x < 32) {
    // =================== GRU scan ===================
    u16* h16 = &sA[0][0];          // 256 u16
    float* part = (float*)&sB[0][0];  // 3*256 floats
    int b = blockIdx.x;
    int j = tid & 255;
    int half = tid >> 8;

    f16x2 w[3][64];
#pragma unroll
    for (int g = 0; g < 3; ++g) {
      const u16* wr = whh16 + (g * 256 + j) * 256 + half * 128;
#pragma unroll
      for (int c = 0; c < 16; ++c) {
        union { f16x8 v8; f16x2 v2[4]; } uu;
        uu.v8 = *(const f16x8*)(wr + c * 8);
        w[g][c * 4 + 0] = uu.v2[0];
        w[g][c * 4 + 1] = uu.v2[1];
        w[g][c * 4 + 2] = uu.v2[2];
        w[g][c * 4 + 3] = uu.v2[3];
      }
    }
    float bh0 = 0.f, bh1 = 0.f, bh2 = 0.f;
    if (half == 0) {
      bh0 = b_hh[j]; bh1 = b_hh[256 + j]; bh2 = b_hh[512 + j];
    }
    if (tid < 256) h16[tid] = 0;  // h = 0
    __syncthreads();

    float h_carry = 0.f;
    for (int t = 0; t < 128; ++t) {
      float xr = 0.f, xu = 0.f, xn = 0.f;
      if (half == 0) {
        const float* gp = gx2 + (t * 32 + b) * 768 + j;
        xr = gp[0]; xu = gp[256]; xn = gp[512];
      }
      float a0 = 0.f, a1 = 0.f, a2 = 0.f;
      const f16x8* hv = (const f16x8*)h16;
#pragma unroll
      for (int c = 0; c < 16; ++c) {
        union { f16x8 v8; f16x2 v2[4]; } hu;
        hu.v8 = hv[half * 16 + c];
#pragma unroll
        for (int p = 0; p < 4; ++p) {
          f16x2 hp = hu.v2[p];
          a0 = FDOT2(w[0][c * 4 + p], hp, a0);
          a1 = FDOT2(w[1][c * 4 + p], hp, a1);
          a2 = FDOT2(w[2][c * 4 + p], hp, a2);
        }
      }
      if (half == 1) {
        part[0 * 256 + j] = a0; part[1 * 256 + j] = a1; part[2 * 256 + j] = a2;
      }
      __syncthreads();
      if (half == 0) {
        float gr = a0 + part[0 * 256 + j] + bh0;
        float gu = a1 + part[1 * 256 + j] + bh1;
        float gn = a2 + part[2 * 256 + j] + bh2;
        float r = 1.f / (1.f + expf(-(xr + gr)));
        float u = 1.f / (1.f + expf(-(xu + gu)));
        float n = tanhf(xn + r * gn);
        float h_new = (1.f - u) * n + u * h_carry;
        h_carry = h_new;
        u16 hh = f2h_bits(h_new);
        h16[j] = hh;
        Hs[(t * 32 + b) * 256 + j] = hh;  // t-major row
      }
      __syncthreads();  // drains Hs stores (vmcnt0) of all threads
      if (((t + 1) & 3) == 0 && tid == 0) {
        __builtin_amdgcn_fence(__ATOMIC_RELEASE, "agent");
        __hip_atomic_store(&flags[b * 4], (unsigned)(t + 1), __ATOMIC_RELAXED,
                           __HIP_MEMORY_SCOPE_AGENT);
      }
    }
  } else {
    // =================== projection tile ===================
    int pid = blockIdx.x - 32;
    int mt = pid / 250, nt = pid % 250;
    int m0 = mt << 7, v0 = nt << 7;
    int wave = tid >> 6, lane = tid & 63;
    int wm = wave >> 1, wn = wave & 1;  // wm: 0..3 (32 rows), wn: 0..1 (64 cols)

    // ---- wait until scan rows [m0, m0+128) are published ----
    {
      unsigned need = (unsigned)(4 * mt + 4);
      if (tid < 64) {
        while (true) {
          unsigned f = __hip_atomic_load(&flags[(tid & 31) * 4],
                                         __ATOMIC_RELAXED,
                                         __HIP_MEMORY_SCOPE_AGENT);
          if (__all(f >= need)) break;
          __builtin_amdgcn_s_sleep(8);
        }
        __builtin_amdgcn_fence(__ATOMIC_ACQUIRE, "agent");
      }
      __syncthreads();
    }

    f32x4 acc[2][4];
#pragma unroll
    for (int i = 0; i < 2; ++i)
#pragma unroll
      for (int j2 = 0; j2 < 4; ++j2) acc[i][j2] = (f32x4){0.f, 0.f, 0.f, 0.f};

    f16x8 va[2], vb[2];
#define LOADC(kc_)                                                        \
    {                                                                     \
      int kb = (kc_) << 6;                                                \
      _Pragma("unroll") for (int q = 0; q < 2; ++q) {                     \
        int gr = q * 512 + tid;                                           \
        int row = gr >> 3, kg = gr & 7;                                   \
        va[q] = *(const f16x8*)(Hs + (m0 + row) * 256 + kb + kg * 8);     \
        vb[q] = *(const f16x8*)(wo16 + (v0 + row) * 256 + kb + kg * 8);   \
      }                                                                   \
    }
#define STORELDS(bsel_)                                                   \
    {                                                                     \
      _Pragma("unroll") for (int q = 0; q < 2; ++q) {                     \
        int gr = q * 512 + tid;                                           \
        int row = gr >> 3, kg = gr & 7;                                   \
        int pg = (gr & ~7) | (kg ^ (row & 7));                            \
        *(f16x8*)&sA[bsel_][pg * 8] = va[q];                              \
        *(f16x8*)&sB[bsel_][pg * 8] = vb[q];                              \
      }                                                                   \
    }

    LOADC(0);
    STORELDS(0);
    __syncthreads();

    for (int kc = 0; kc < 4; ++kc) {
      int bsel = kc & 1;
      if (kc < 3) LOADC(kc + 1);
#pragma unroll
      for (int ks = 0; ks < 2; ++ks) {
        f16x8 af[2], bf[4];
        int kg = ks * 4 + (lane >> 4);
#pragma unroll
        for (int i = 0; i < 2; ++i) {
          int row = wm * 32 + i * 16 + (lane & 15);
          af[i] = *(const f16x8*)&sA[bsel][(row * 8 + (kg ^ (row & 7))) * 8];
        }
#pragma unroll
        for (int j2 = 0; j2 < 4; ++j2) {
          int vrow = wn * 64 + j2 * 16 + (lane & 15);
          bf[j2] = *(const f16x8*)&sB[bsel][(vrow * 8 + (kg ^ (vrow & 7))) * 8];
        }
#pragma unroll
        for (int i = 0; i < 2; ++i)
#pragma unroll
          for (int j2 = 0; j2 < 4; ++j2)
            acc[i][j2] = __builtin_amdgcn_mfma_f32_16x16x32_f16(
                af[i], bf[j2], acc[i][j2], 0, 0, 0);
      }
      if (kc < 3) STORELDS(bsel ^ 1);
      __syncthreads();
    }
#undef LOADC
#undef STORELDS

    int vcol = v0 + wn * 64 + (lane & 15);
    int nbase = m0 + wm * 32 + (lane >> 4) * 4;
#pragma unroll
    for (int i = 0; i < 2; ++i) {
#pragma unroll
      for (int j2 = 0; j2 < 4; ++j2) {
        int v = vcol + j2 * 16;
        float bias = bo[v];
#pragma unroll
        for (int r = 0; r < 4; ++r) {
          int n = nbase + i * 16 + r;          // n = t*32 + b
          long orow = (long)(n & 31) * 128 + (n >> 5);
          __builtin_nontemporal_store(acc[i][j2][r] + bias,
                                      &out[orow * 32000 + v]);
        }
      }
    }
  }
}

// ---------------------------------------------------------------------------
extern "C" void kernel_launch(void* const* d_in, const int* in_sizes, int n_in,
                              void* d_out, int out_size, void* d_ws, size_t ws_size,
                              hipStream_t stream) {
  const int*   x       = (const int*)d_in[0];
  const int*   y_in    = (const int*)d_in[1];
  const float* emb     = (const float*)d_in[2];
  const float* dec_emb = (const float*)d_in[3];
  const float* Wt      = (const float*)d_in[4];
  const float* bt      = (const float*)d_in[5];
  const float* W_ih    = (const float*)d_in[6];
  const float* W_hh    = (const float*)d_in[7];
  const float* b_ih    = (const float*)d_in[8];
  const float* b_hh    = (const float*)d_in[9];
  const float* Wo      = (const float*)d_in[10];
  const float* bo      = (const float*)d_in[11];
  float* out = (float*)d_out;
  char* ws = (char*)d_ws;

  unsigned* flags = (unsigned*)(ws + 0);       // 32 slots x 16B = 512 B
  float* zbuf     = (float*)(ws + 33024);      // 32*256*4   = 32768
  u16*   Hs       = (u16*)(ws + 98560);        // 4096*256*2 = 2097152
  u16*   whh16    = (u16*)(ws + 2195712);      // 768*256*2  = 393216
  u16*   wo16     = (u16*)(ws + 2588928);      // 32000*256*2= 16384000
  float* gx2      = (float*)(ws + 18972928);   // 4096*768*4 = 12582912
  // total: 31555840 bytes

  (void)hipMemsetAsync(flags, 0, 512, stream);
  k_pe<<<2080, 256, 0, stream>>>(x, emb, Wt, bt, W_hh, Wo, zbuf, whh16, wo16);
  k_gx<<<768, 256, 0, stream>>>(W_ih, b_ih, dec_emb, y_in, zbuf, gx2);
  k_mega<<<8032, 512, 0, stream>>>(whh16, b_hh, gx2, Hs, wo16, bo, out, flags);
}